// Round 2
// baseline (561.698 us; speedup 1.0000x reference)
//
#include <hip/hip_runtime.h>

#define IMG_W 8192
#define IMG_H 8192
#define KS 15
#define RAD 7
#define TW 64
#define TH 64
#define BLOCK 256
#define SROWS 78            // TH + 2*RAD
#define SIN_STRIDE 80       // 80 floats/row: global cols [col0-8, col0+71], 16B aligned
#define MID_STRIDE 68       // padded (not 64) to break stage-C row aliasing

__device__ __forceinline__ int reflect_idx(int p, int n) {
    if (p < 0) p = -p;
    if (p >= n) p = 2 * n - 2 - p;
    return p;
}

__global__ __launch_bounds__(BLOCK)
void gauss15_fused(const float* __restrict__ in,
                   const float* __restrict__ k2d,
                   float* __restrict__ out) {
    __shared__ float s_in[SROWS * SIN_STRIDE];   // 24.96 KB
    __shared__ float s_mid[SROWS * MID_STRIDE];  // 21.2 KB
    __shared__ float s_kx[KS], s_ky[KS];

    const int t = threadIdx.x;
    const int col0 = blockIdx.x * TW;
    const int row0 = blockIdx.y * TH;

    // Recover separable 1D kernels (K2 = outer(ky,kx), each sums to 1)
    if (t < KS) {
        float sx = 0.f, sy = 0.f;
        #pragma unroll
        for (int i = 0; i < KS; i++) {
            sx += k2d[i * KS + t];
            sy += k2d[t * KS + i];
        }
        s_kx[t] = sx; s_ky[t] = sy;
    }

    const bool border = (blockIdx.x == 0) | (blockIdx.x == gridDim.x - 1) |
                        (blockIdx.y == 0) | (blockIdx.y == gridDim.y - 1);

    // ---- Stage A: global -> LDS. s_in col c == global col0-8+c, row r == row0-7+r ----
    if (!border) {
        // fast path: float4 loads, no reflect. 78 rows x 20 float4 = 1560 tasks.
        for (int idx = t; idx < SROWS * 20; idx += BLOCK) {
            int r = idx / 20;
            int c4 = idx - r * 20;
            const float4 v = *(const float4*)&in[(size_t)(row0 - RAD + r) * IMG_W
                                                 + (col0 - 8 + c4 * 4)];
            *(float4*)&s_in[r * SIN_STRIDE + c4 * 4] = v;
        }
    } else {
        for (int idx = t; idx < SROWS * SIN_STRIDE; idx += BLOCK) {
            int r = idx / SIN_STRIDE;
            int c = idx - r * SIN_STRIDE;
            int gr = reflect_idx(row0 - RAD + r, IMG_H);
            int gc = reflect_idx(col0 - 8 + c, IMG_W);
            s_in[r * SIN_STRIDE + c] = in[(size_t)gr * IMG_W + gc];
        }
    }
    __syncthreads();

    float kx[KS];
    #pragma unroll
    for (int i = 0; i < KS; i++) kx[i] = s_kx[i];

    // ---- Stage B: horizontal conv, 16 outputs/task. 78 rows x 4 groups = 312 tasks ----
    // output col j needs s_in cols j+1 .. j+15 (shifted layout)
    for (int tau = t; tau < SROWS * 4; tau += BLOCK) {
        int r = tau >> 2;
        int q = tau & 3;
        const float* rowp = &s_in[r * SIN_STRIDE + q * 16];
        float f[32];
        #pragma unroll
        for (int m = 0; m < 8; m++)
            *(float4*)(f + 4 * m) = *(const float4*)(rowp + 4 * m);
        float acc[16];
        #pragma unroll
        for (int k = 0; k < 16; k++) acc[k] = 0.f;
        #pragma unroll
        for (int j = 0; j < KS; j++) {
            float w = kx[j];
            #pragma unroll
            for (int k = 0; k < 16; k++)
                acc[k] += f[k + 1 + j] * w;
        }
        float* midp = &s_mid[r * MID_STRIDE + q * 16];
        #pragma unroll
        for (int m = 0; m < 4; m++)
            *(float4*)(midp + 4 * m) = make_float4(acc[4*m], acc[4*m+1], acc[4*m+2], acc[4*m+3]);
    }
    __syncthreads();

    float ky[KS];
    #pragma unroll
    for (int i = 0; i < KS; i++) ky[i] = s_ky[i];

    // ---- Stage C: vertical conv. Thread (cg,rg): 4 cols x 4 rows; 18 mid rows ----
    // s_mid row m == output row m-7; out row y needs s_mid rows y..y+14
    const int cg = t & 15;
    const int rg = t >> 4;
    const int c = cg * 4;
    const int r0 = rg * 4;

    float4 acc[4];
    #pragma unroll
    for (int q = 0; q < 4; q++) acc[q] = make_float4(0.f, 0.f, 0.f, 0.f);

    #pragma unroll
    for (int i = 0; i < KS + 3; i++) {
        float4 v = *(const float4*)&s_mid[(r0 + i) * MID_STRIDE + c];
        #pragma unroll
        for (int q = 0; q < 4; q++) {
            int j = i - q;
            if (j >= 0 && j < KS) {
                float w = ky[j];
                acc[q].x += v.x * w;
                acc[q].y += v.y * w;
                acc[q].z += v.z * w;
                acc[q].w += v.w * w;
            }
        }
    }

    #pragma unroll
    for (int q = 0; q < 4; q++) {
        *(float4*)&out[(size_t)(row0 + r0 + q) * IMG_W + col0 + c] = acc[q];
    }
}

extern "C" void kernel_launch(void* const* d_in, const int* in_sizes, int n_in,
                              void* d_out, int out_size, void* d_ws, size_t ws_size,
                              hipStream_t stream) {
    const float* img = (const float*)d_in[0];
    const float* k2d = (const float*)d_in[1];
    float* out = (float*)d_out;

    dim3 grid(IMG_W / TW, IMG_H / TH);
    gauss15_fused<<<grid, BLOCK, 0, stream>>>(img, k2d, out);
}